// Round 2
// baseline (339.553 us; speedup 1.0000x reference)
//
#include <hip/hip_runtime.h>
#include <hip/hip_bf16.h>

#define NNODES 50000
#define NEDGES 640000
#define HID 128
#define NWG 500
#define WAVES 8
#define EPW (WAVES * 32)   // 256 edges per WG per sweep

typedef __attribute__((ext_vector_type(8)))  short  short8;
typedef __attribute__((ext_vector_type(16))) float  f32x16;
typedef __attribute__((ext_vector_type(4)))  float  f32x4v;

static __device__ __forceinline__ short f2bf(float x) {
    return __builtin_bit_cast(short, __float2bfloat16(x));
}

// ---- prepass: h (f32) -> bf16 rows in workspace ----
__global__ __launch_bounds__(256)
void h_to_bf16(const float* __restrict__ h, unsigned short* __restrict__ hb) {
    size_t i = ((size_t)blockIdx.x * 256 + threadIdx.x) * 8;
    if (i >= (size_t)NNODES * HID) return;
    f32x4v a0 = *(const f32x4v*)(h + i);
    f32x4v a1 = *(const f32x4v*)(h + i + 4);
    short8 s;
    s[0] = f2bf(a0.x); s[1] = f2bf(a0.y); s[2] = f2bf(a0.z); s[3] = f2bf(a0.w);
    s[4] = f2bf(a1.x); s[5] = f2bf(a1.y); s[6] = f2bf(a1.z); s[7] = f2bf(a1.w);
    *(short8*)(hb + i) = s;
}

template<bool BFH>
__global__ __launch_bounds__(512, 4)
void edgehead_mlp(const float* __restrict__ h,
                  const unsigned short* __restrict__ hb,
                  const int* __restrict__ ei,
                  const float* __restrict__ ea,
                  const float* __restrict__ W1,
                  const float* __restrict__ b1,
                  const float* __restrict__ W2,
                  const float* __restrict__ b2,
                  float* __restrict__ out)
{
    // W1^T staged as bf16: [col][k] in 16B chunks, chunk index XOR-swizzled by (col&7)
    __shared__ short8 w1t8[128 * 32];   // k = 0..255   (64 KB)
    __shared__ short8 w1e8[128 * 3];    // k = 256..271: [w1[256], w1[257], b1, pad] (6 KB)
    short* w1s  = (short*)w1t8;
    short* w1es = (short*)w1e8;

    const int tid = threadIdx.x;

    for (int idx = tid; idx < 256 * HID; idx += 512) {
        int k = idx >> 7, col = idx & 127;
        w1s[col * 256 + (k ^ ((col & 7) << 3))] = f2bf(W1[idx]);
    }
    if (tid < HID) {
        int col = tid;
        int base = col * 24;
        w1es[base + 0] = f2bf(W1[256 * HID + col]);
        w1es[base + 1] = f2bf(W1[257 * HID + col]);
        w1es[base + 2] = f2bf(b1[col]);
        #pragma unroll
        for (int j = 3; j < 16; ++j) w1es[base + j] = 0;
    }
    __syncthreads();

    const int lane = tid & 63;
    const int wid  = tid >> 6;
    const int l31  = lane & 31;
    const int grp  = lane >> 5;

    // runtime dtype hedge: int64 edge_index read as int32 -> odd slots zero
    const bool is64 = (ei[1] == 0) && (ei[3] == 0) && (ei[5] == 0) && (ei[7] == 0);
    const long long* ei64 = (const long long*)ei;

    float w2v[4];
    #pragma unroll
    for (int nt = 0; nt < 4; ++nt) w2v[nt] = W2[nt * 32 + l31];
    const float b2v = b2[0];

    const int estride = NWG * EPW;
    int ebase = blockIdx.x * EPW + wid * 32;

    // prefetch first tile's indices + edge attrs
    int u = 0, v = 0; float ea0 = 0.f, ea1 = 0.f;
    if (ebase < NEDGES) {
        const int e = ebase + l31;
        u = is64 ? (int)ei64[e] : ei[e];
        v = is64 ? (int)ei64[NEDGES + e] : ei[NEDGES + e];
        ea0 = ea[2 * e]; ea1 = ea[2 * e + 1];
    }

    for (; ebase < NEDGES; ebase += estride) {
        const int u_c = u, v_c = v;
        const float ea0_c = ea0, ea1_c = ea1;

        // prefetch next tile's indices + edge attrs (breaks idx->gather chain)
        {
            const int nb = ebase + estride;
            if (nb < NEDGES) {
                const int en = nb + l31;
                u = is64 ? (int)ei64[en] : ei[en];
                v = is64 ? (int)ei64[NEDGES + en] : ei[NEDGES + en];
                ea0 = ea[2 * en]; ea1 = ea[2 * en + 1];
            }
        }

        const unsigned short* pu16 = BFH ? hb + (size_t)u_c * HID + grp * 8 : nullptr;
        const unsigned short* pv16 = BFH ? hb + (size_t)v_c * HID + grp * 8 : nullptr;
        const float* pu32 = BFH ? nullptr : h + (size_t)u_c * HID + grp * 8;
        const float* pv32 = BFH ? nullptr : h + (size_t)v_c * HID + grp * 8;

        f32x16 acc[4];
        #pragma unroll
        for (int nt = 0; nt < 4; ++nt)
            #pragma unroll
            for (int r = 0; r < 16; ++r) acc[nt][r] = 0.f;

        #pragma unroll
        for (int ks = 0; ks < 17; ++ks) {
            short8 af;
            if (ks < 16) {
                if (BFH) {
                    const unsigned short* p = (ks < 8) ? (pu16 + ks * 16) : (pv16 + (ks - 8) * 16);
                    af = *(const short8*)p;
                } else {
                    const float* p = (ks < 8) ? (pu32 + ks * 16) : (pv32 + (ks - 8) * 16);
                    f32x4v a0 = *(const f32x4v*)(p);
                    f32x4v a1 = *(const f32x4v*)(p + 4);
                    af[0] = f2bf(a0.x); af[1] = f2bf(a0.y);
                    af[2] = f2bf(a0.z); af[3] = f2bf(a0.w);
                    af[4] = f2bf(a1.x); af[5] = f2bf(a1.y);
                    af[6] = f2bf(a1.z); af[7] = f2bf(a1.w);
                }
            } else {
                af[0] = grp ? (short)0 : f2bf(ea0_c);
                af[1] = grp ? (short)0 : f2bf(ea1_c);
                af[2] = grp ? (short)0 : (short)0x3F80;  // 1.0 bf16 -> picks up b1 row
                af[3] = 0; af[4] = 0; af[5] = 0; af[6] = 0; af[7] = 0;
            }
            #pragma unroll
            for (int nt = 0; nt < 4; ++nt) {
                const int col = nt * 32 + l31;
                short8 bf = (ks < 16)
                    ? w1t8[col * 32 + ((ks * 2 + grp) ^ (l31 & 7))]
                    : w1e8[col * 3 + grp];
                acc[nt] = __builtin_amdgcn_mfma_f32_32x32x16_bf16(af, bf, acc[nt], 0, 0, 0);
            }
        }

        // ---- epilogue: relu * W2, reduce over 128 cols ----
        float pr[16];
        #pragma unroll
        for (int r = 0; r < 16; ++r) {
            float s = fmaxf(acc[0][r], 0.f) * w2v[0];
            s = fmaf(fmaxf(acc[1][r], 0.f), w2v[1], s);
            s = fmaf(fmaxf(acc[2][r], 0.f), w2v[2], s);
            s = fmaf(fmaxf(acc[3][r], 0.f), w2v[3], s);
            pr[r] = s;
        }

        #define FOLD(MASK, A, B) { \
            const bool hi = (lane & MASK) != 0; \
            float snd = hi ? pr[A] : pr[B]; \
            float kp  = hi ? pr[B] : pr[A]; \
            pr[A] = kp + __shfl_xor(snd, MASK, 64); }
        #pragma unroll
        for (int i = 0; i < 8; ++i) FOLD(1, i, i + 8)
        #pragma unroll
        for (int i = 0; i < 4; ++i) FOLD(2, i, i + 4)
        #pragma unroll
        for (int i = 0; i < 2; ++i) FOLD(4, i, i + 2)
        FOLD(8, 0, 1)
        #undef FOLD
        float val = pr[0] + __shfl_xor(pr[0], 16, 64);

        const int reff = ((lane & 1) << 3) | ((lane & 2) << 1) | ((lane & 4) >> 1) | ((lane & 8) >> 3);
        const int row  = (reff & 3) + ((reff >> 2) << 3) + grp * 4;
        if ((lane & 16) == 0) out[ebase + row] = val + b2v;
    }
}

extern "C" void kernel_launch(void* const* d_in, const int* in_sizes, int n_in,
                              void* d_out, int out_size, void* d_ws, size_t ws_size,
                              hipStream_t stream) {
    const float* h  = (const float*)d_in[0];
    const int*   ei = (const int*)d_in[1];
    const float* ea = (const float*)d_in[2];
    const float* W1 = (const float*)d_in[3];
    const float* b1 = (const float*)d_in[4];
    const float* W2 = (const float*)d_in[5];
    const float* b2 = (const float*)d_in[6];
    float* out = (float*)d_out;

    const size_t need = (size_t)NNODES * HID * sizeof(unsigned short);
    if (ws_size >= need) {
        unsigned short* hb = (unsigned short*)d_ws;
        const int nconv = (NNODES * HID + 8 * 256 - 1) / (8 * 256);
        hipLaunchKernelGGL(h_to_bf16, dim3(nconv), dim3(256), 0, stream, h, hb);
        hipLaunchKernelGGL((edgehead_mlp<true>), dim3(NWG), dim3(512), 0, stream,
                           h, hb, ei, ea, W1, b1, W2, b2, out);
    } else {
        hipLaunchKernelGGL((edgehead_mlp<false>), dim3(NWG), dim3(512), 0, stream,
                           h, (const unsigned short*)nullptr, ei, ea, W1, b1, W2, b2, out);
    }
}

// Round 3
// 176.849 us; speedup vs baseline: 1.9200x; 1.9200x over previous
//
#include <hip/hip_runtime.h>
#include <hip/hip_bf16.h>

#define NNODES 50000
#define NEDGES 640000
#define HID 128
#define NWG 500
#define EPW 128   // edges per WG per sweep (4 waves x 32)

typedef __attribute__((ext_vector_type(8)))  short  short8;
typedef __attribute__((ext_vector_type(16))) float  f32x16;
typedef __attribute__((ext_vector_type(4)))  float  f32x4v;

static __device__ __forceinline__ short f2bf(float x) {
    return __builtin_bit_cast(short, __float2bfloat16(x));
}

// ---- prepass: h (f32) -> bf16 rows in workspace ----
__global__ __launch_bounds__(256)
void h_to_bf16(const float* __restrict__ h, unsigned short* __restrict__ hb) {
    size_t i = ((size_t)blockIdx.x * 256 + threadIdx.x) * 8;
    if (i >= (size_t)NNODES * HID) return;
    f32x4v a0 = *(const f32x4v*)(h + i);
    f32x4v a1 = *(const f32x4v*)(h + i + 4);
    short8 s;
    s[0] = f2bf(a0.x); s[1] = f2bf(a0.y); s[2] = f2bf(a0.z); s[3] = f2bf(a0.w);
    s[4] = f2bf(a1.x); s[5] = f2bf(a1.y); s[6] = f2bf(a1.z); s[7] = f2bf(a1.w);
    *(short8*)(hb + i) = s;
}

template<bool BFH>
__global__ __launch_bounds__(256, 2)
void edgehead_mlp(const float* __restrict__ h,
                  const unsigned short* __restrict__ hb,
                  const int* __restrict__ ei,
                  const float* __restrict__ ea,
                  const float* __restrict__ W1,
                  const float* __restrict__ b1,
                  const float* __restrict__ W2,
                  const float* __restrict__ b2,
                  float* __restrict__ out)
{
    // W1^T staged as bf16: [col][k] in 16B chunks, chunk index XOR-swizzled by (col&7)
    __shared__ short8 w1t8[128 * 32];   // k = 0..255   (64 KB)
    __shared__ short8 w1e8[128 * 3];    // k = 256..271: [w1[256], w1[257], b1, pad] (6 KB)
    short* w1s  = (short*)w1t8;
    short* w1es = (short*)w1e8;

    const int tid = threadIdx.x;

    for (int idx = tid; idx < 256 * HID; idx += 256) {
        int k = idx >> 7, col = idx & 127;
        w1s[col * 256 + (k ^ ((col & 7) << 3))] = f2bf(W1[idx]);
    }
    if (tid < HID) {
        int col = tid;
        int base = col * 24;
        w1es[base + 0] = f2bf(W1[256 * HID + col]);
        w1es[base + 1] = f2bf(W1[257 * HID + col]);
        w1es[base + 2] = f2bf(b1[col]);
        #pragma unroll
        for (int j = 3; j < 16; ++j) w1es[base + j] = 0;
    }
    __syncthreads();

    const int lane = tid & 63;
    const int wid  = tid >> 6;
    const int l31  = lane & 31;
    const int grp  = lane >> 5;

    // runtime dtype hedge: int64 edge_index read as int32 -> odd slots zero
    const bool is64 = (ei[1] == 0) && (ei[3] == 0) && (ei[5] == 0) && (ei[7] == 0);
    const long long* ei64 = (const long long*)ei;

    float w2v[4];
    #pragma unroll
    for (int nt = 0; nt < 4; ++nt) w2v[nt] = W2[nt * 32 + l31];
    const float b2v = b2[0];

    const int estride = NWG * EPW;
    int ebase = blockIdx.x * EPW + wid * 32;

    // prefetch first tile's indices + edge attrs
    int u = 0, v = 0; float ea0 = 0.f, ea1 = 0.f;
    if (ebase < NEDGES) {
        const int e = ebase + l31;
        u = is64 ? (int)ei64[e] : ei[e];
        v = is64 ? (int)ei64[NEDGES + e] : ei[NEDGES + e];
        ea0 = ea[2 * e]; ea1 = ea[2 * e + 1];
    }

    for (; ebase < NEDGES; ebase += estride) {
        const int u_c = u, v_c = v;
        const float ea0_c = ea0, ea1_c = ea1;

        // prefetch next tile's indices + edge attrs (breaks idx->gather chain)
        {
            const int nb = ebase + estride;
            if (nb < NEDGES) {
                const int en = nb + l31;
                u = is64 ? (int)ei64[en] : ei[en];
                v = is64 ? (int)ei64[NEDGES + en] : ei[NEDGES + en];
                ea0 = ea[2 * en]; ea1 = ea[2 * en + 1];
            }
        }

        // ---- issue ALL 16 A-fragment gathers up front (max MLP in flight) ----
        short8 afv[16];
        if (BFH) {
            const unsigned short* pu16 = hb + (size_t)u_c * HID + grp * 8;
            const unsigned short* pv16 = hb + (size_t)v_c * HID + grp * 8;
            #pragma unroll
            for (int ks = 0; ks < 8; ++ks)  afv[ks]     = *(const short8*)(pu16 + ks * 16);
            #pragma unroll
            for (int ks = 0; ks < 8; ++ks)  afv[8 + ks] = *(const short8*)(pv16 + ks * 16);
        } else {
            const float* pu32 = h + (size_t)u_c * HID + grp * 8;
            const float* pv32 = h + (size_t)v_c * HID + grp * 8;
            #pragma unroll
            for (int ks = 0; ks < 16; ++ks) {
                const float* p = (ks < 8) ? (pu32 + ks * 16) : (pv32 + (ks - 8) * 16);
                f32x4v a0 = *(const f32x4v*)(p);
                f32x4v a1 = *(const f32x4v*)(p + 4);
                short8 af;
                af[0] = f2bf(a0.x); af[1] = f2bf(a0.y);
                af[2] = f2bf(a0.z); af[3] = f2bf(a0.w);
                af[4] = f2bf(a1.x); af[5] = f2bf(a1.y);
                af[6] = f2bf(a1.z); af[7] = f2bf(a1.w);
                afv[ks] = af;
            }
        }

        f32x16 acc[4];
        #pragma unroll
        for (int nt = 0; nt < 4; ++nt)
            #pragma unroll
            for (int r = 0; r < 16; ++r) acc[nt][r] = 0.f;

        #pragma unroll
        for (int ks = 0; ks < 17; ++ks) {
            short8 af;
            if (ks < 16) {
                af = afv[ks];
            } else {
                af[0] = grp ? (short)0 : f2bf(ea0_c);
                af[1] = grp ? (short)0 : f2bf(ea1_c);
                af[2] = grp ? (short)0 : (short)0x3F80;  // 1.0 bf16 -> picks up b1 row
                af[3] = 0; af[4] = 0; af[5] = 0; af[6] = 0; af[7] = 0;
            }
            #pragma unroll
            for (int nt = 0; nt < 4; ++nt) {
                const int col = nt * 32 + l31;
                short8 bf = (ks < 16)
                    ? w1t8[col * 32 + ((ks * 2 + grp) ^ (l31 & 7))]
                    : w1e8[col * 3 + grp];
                acc[nt] = __builtin_amdgcn_mfma_f32_32x32x16_bf16(af, bf, acc[nt], 0, 0, 0);
            }
        }

        // ---- epilogue: relu * W2, reduce over 128 cols ----
        float pr[16];
        #pragma unroll
        for (int r = 0; r < 16; ++r) {
            float s = fmaxf(acc[0][r], 0.f) * w2v[0];
            s = fmaf(fmaxf(acc[1][r], 0.f), w2v[1], s);
            s = fmaf(fmaxf(acc[2][r], 0.f), w2v[2], s);
            s = fmaf(fmaxf(acc[3][r], 0.f), w2v[3], s);
            pr[r] = s;
        }

        #define FOLD(MASK, A, B) { \
            const bool hi = (lane & MASK) != 0; \
            float snd = hi ? pr[A] : pr[B]; \
            float kp  = hi ? pr[B] : pr[A]; \
            pr[A] = kp + __shfl_xor(snd, MASK, 64); }
        #pragma unroll
        for (int i = 0; i < 8; ++i) FOLD(1, i, i + 8)
        #pragma unroll
        for (int i = 0; i < 4; ++i) FOLD(2, i, i + 4)
        #pragma unroll
        for (int i = 0; i < 2; ++i) FOLD(4, i, i + 2)
        FOLD(8, 0, 1)
        #undef FOLD
        float val = pr[0] + __shfl_xor(pr[0], 16, 64);

        const int reff = ((lane & 1) << 3) | ((lane & 2) << 1) | ((lane & 4) >> 1) | ((lane & 8) >> 3);
        const int row  = (reff & 3) + ((reff >> 2) << 3) + grp * 4;
        if ((lane & 16) == 0) out[ebase + row] = val + b2v;
    }
}

extern "C" void kernel_launch(void* const* d_in, const int* in_sizes, int n_in,
                              void* d_out, int out_size, void* d_ws, size_t ws_size,
                              hipStream_t stream) {
    const float* h  = (const float*)d_in[0];
    const int*   ei = (const int*)d_in[1];
    const float* ea = (const float*)d_in[2];
    const float* W1 = (const float*)d_in[3];
    const float* b1 = (const float*)d_in[4];
    const float* W2 = (const float*)d_in[5];
    const float* b2 = (const float*)d_in[6];
    float* out = (float*)d_out;

    const size_t need = (size_t)NNODES * HID * sizeof(unsigned short);
    if (ws_size >= need) {
        unsigned short* hb = (unsigned short*)d_ws;
        const int nconv = (NNODES * HID + 8 * 256 - 1) / (8 * 256);
        hipLaunchKernelGGL(h_to_bf16, dim3(nconv), dim3(256), 0, stream, h, hb);
        hipLaunchKernelGGL((edgehead_mlp<true>), dim3(NWG), dim3(256), 0, stream,
                           h, hb, ei, ea, W1, b1, W2, b2, out);
    } else {
        hipLaunchKernelGGL((edgehead_mlp<false>), dim3(NWG), dim3(256), 0, stream,
                           h, (const unsigned short*)nullptr, ei, ea, W1, b1, W2, b2, out);
    }
}

// Round 4
// 79.476 us; speedup vs baseline: 4.2724x; 2.2252x over previous
//
#include <hip/hip_runtime.h>
#include <hip/hip_bf16.h>

#define NNODES 50000
#define NEDGES 640000
#define HID 128

typedef __attribute__((ext_vector_type(8)))  short  short8;
typedef __attribute__((ext_vector_type(16))) float  f32x16;
typedef __attribute__((ext_vector_type(4)))  float  f32x4v;

static __device__ __forceinline__ short f2bf(float x) {
    return __builtin_bit_cast(short, __float2bfloat16(x));
}
static __device__ __forceinline__ float bf2f(unsigned short x) {
    unsigned int u = ((unsigned int)x) << 16;
    return __builtin_bit_cast(float, u);
}

// =====================================================================
// Kernel 1: pre[n][0:128] = h[n]*W1[0:128] + b1 ; pre[n][128:256] = h[n]*W1[128:256]
// M=50000, N=256, K=128, bf16 MFMA, output bf16.
// =====================================================================
__global__ __launch_bounds__(256, 1)
void gemm_pre(const float* __restrict__ h,
              const float* __restrict__ W1,
              const float* __restrict__ b1,
              unsigned short* __restrict__ pre)
{
    // W1cat^T staged bf16: [col 0..255][k 0..127], 16B chunks, chunk ^= (col&7)
    __shared__ short8 w1s8[256 * 16];   // 64 KB
    short* w1s = (short*)w1s8;
    const int tid = threadIdx.x;

    for (int idx = tid; idx < 256 * 128; idx += 256) {
        int k = idx >> 8, col = idx & 255;
        float val = (col < 128) ? W1[k * 128 + col]
                                : W1[(128 + k) * 128 + (col - 128)];
        int c = (k >> 3) ^ (col & 7);
        w1s[col * 128 + c * 8 + (k & 7)] = f2bf(val);
    }
    __syncthreads();

    const int lane = tid & 63;
    const int wid  = tid >> 6;
    const int l31  = lane & 31;
    const int grp  = lane >> 5;

    const int mb = blockIdx.x * 128 + wid * 32;
    int arow = mb + l31;
    if (arow > NNODES - 1) arow = NNODES - 1;
    const float* ap = h + (size_t)arow * HID + grp * 8;

    f32x16 acc[8];
    #pragma unroll
    for (int nt = 0; nt < 8; ++nt)
        #pragma unroll
        for (int r = 0; r < 16; ++r) acc[nt][r] = 0.f;

    #pragma unroll
    for (int ks = 0; ks < 8; ++ks) {
        f32x4v a0 = *(const f32x4v*)(ap + ks * 16);
        f32x4v a1 = *(const f32x4v*)(ap + ks * 16 + 4);
        short8 af;
        af[0] = f2bf(a0.x); af[1] = f2bf(a0.y); af[2] = f2bf(a0.z); af[3] = f2bf(a0.w);
        af[4] = f2bf(a1.x); af[5] = f2bf(a1.y); af[6] = f2bf(a1.z); af[7] = f2bf(a1.w);
        #pragma unroll
        for (int nt = 0; nt < 8; ++nt) {
            const int col = nt * 32 + l31;
            const int c = (ks * 2 + grp) ^ (col & 7);
            short8 bf = w1s8[col * 16 + c];
            acc[nt] = __builtin_amdgcn_mfma_f32_32x32x16_bf16(af, bf, acc[nt], 0, 0, 0);
        }
    }

    float b1v[8];
    #pragma unroll
    for (int nt = 0; nt < 8; ++nt)
        b1v[nt] = (nt < 4) ? b1[nt * 32 + l31] : 0.f;

    #pragma unroll
    for (int r = 0; r < 16; ++r) {
        const int row = mb + ((r & 3) + 8 * (r >> 2) + 4 * grp);
        if (row < NNODES) {
            #pragma unroll
            for (int nt = 0; nt < 8; ++nt)
                pre[(size_t)row * 256 + nt * 32 + l31] =
                    (unsigned short)f2bf(acc[nt][r] + b1v[nt]);
        }
    }
}

// =====================================================================
// Kernel 2: per-edge apply. 8 lanes per edge, 16 cols each.
// out[e] = relu(pre_u[u] + pre_v[v] + ea0*W1r256 + ea1*W1r257) . W2 + b2
// =====================================================================
#define NBLK 2048
#define EPI  32            // edges per block per iter (256 thr / 8)
#define ESTRIDE (NBLK * EPI)

__global__ __launch_bounds__(256, 4)
void edge_apply(const unsigned short* __restrict__ pre,
                const int* __restrict__ ei,
                const float* __restrict__ ea,
                const float* __restrict__ W1,
                const float* __restrict__ W2,
                const float* __restrict__ b2,
                float* __restrict__ out)
{
    const int tid  = threadIdx.x;
    const int sub  = tid & 7;          // column sub-block within edge
    const int gid0 = blockIdx.x * EPI + (tid >> 3);

    // per-lane constants: 16 cols j = sub*16 + i
    float r256v[16], r257v[16], w2v[16];
    #pragma unroll
    for (int q = 0; q < 4; ++q) {
        f32x4v a = *(const f32x4v*)(W1 + 256 * HID + sub * 16 + q * 4);
        f32x4v b = *(const f32x4v*)(W1 + 257 * HID + sub * 16 + q * 4);
        f32x4v c = *(const f32x4v*)(W2 + sub * 16 + q * 4);
        r256v[q*4+0]=a.x; r256v[q*4+1]=a.y; r256v[q*4+2]=a.z; r256v[q*4+3]=a.w;
        r257v[q*4+0]=b.x; r257v[q*4+1]=b.y; r257v[q*4+2]=b.z; r257v[q*4+3]=b.w;
        w2v [q*4+0]=c.x; w2v [q*4+1]=c.y; w2v [q*4+2]=c.z; w2v [q*4+3]=c.w;
    }
    const float b2v = b2[0];

    const bool is64 = (ei[1] == 0) && (ei[3] == 0) && (ei[5] == 0) && (ei[7] == 0);
    const long long* ei64 = (const long long*)ei;

    int e = gid0;
    int u = 0, v = 0; float ea0 = 0.f, ea1 = 0.f;
    if (e < NEDGES) {
        u = is64 ? (int)ei64[e] : ei[e];
        v = is64 ? (int)ei64[NEDGES + e] : ei[NEDGES + e];
        ea0 = ea[2 * e]; ea1 = ea[2 * e + 1];
    }

    for (; e < NEDGES; e += ESTRIDE) {
        const int u_c = u, v_c = v;
        const float ea0_c = ea0, ea1_c = ea1;
        // prefetch next iteration's indices
        {
            const int en = e + ESTRIDE;
            if (en < NEDGES) {
                u = is64 ? (int)ei64[en] : ei[en];
                v = is64 ? (int)ei64[NEDGES + en] : ei[NEDGES + en];
                ea0 = ea[2 * en]; ea1 = ea[2 * en + 1];
            }
        }

        const unsigned short* pu = pre + (size_t)u_c * 256 + sub * 16;
        const unsigned short* pv = pre + (size_t)v_c * 256 + 128 + sub * 16;
        short8 g0 = *(const short8*)(pu);
        short8 g1 = *(const short8*)(pu + 8);
        short8 g2 = *(const short8*)(pv);
        short8 g3 = *(const short8*)(pv + 8);

        float s = 0.f;
        #pragma unroll
        for (int i = 0; i < 8; ++i) {
            float hu = bf2f((unsigned short)g0[i]);
            float hv = bf2f((unsigned short)g2[i]);
            float hid = hu + hv;
            hid = fmaf(ea0_c, r256v[i], hid);
            hid = fmaf(ea1_c, r257v[i], hid);
            s = fmaf(fmaxf(hid, 0.f), w2v[i], s);
        }
        #pragma unroll
        for (int i = 0; i < 8; ++i) {
            float hu = bf2f((unsigned short)g1[i]);
            float hv = bf2f((unsigned short)g3[i]);
            float hid = hu + hv;
            hid = fmaf(ea0_c, r256v[8 + i], hid);
            hid = fmaf(ea1_c, r257v[8 + i], hid);
            s = fmaf(fmaxf(hid, 0.f), w2v[8 + i], s);
        }

        // reduce across the 8 sub-lanes
        s += __shfl_xor(s, 1, 64);
        s += __shfl_xor(s, 2, 64);
        s += __shfl_xor(s, 4, 64);
        if (sub == 0) out[e] = s + b2v;
    }
}

// =====================================================================
// Fallback (ws too small): monolithic f32-gather MFMA kernel (R1 shape)
// =====================================================================
#define NWG 500
#define EPW 128

__global__ __launch_bounds__(256, 2)
void edgehead_mono(const float* __restrict__ h,
                   const int* __restrict__ ei,
                   const float* __restrict__ ea,
                   const float* __restrict__ W1,
                   const float* __restrict__ b1,
                   const float* __restrict__ W2,
                   const float* __restrict__ b2,
                   float* __restrict__ out)
{
    __shared__ short8 w1t8[128 * 32];
    __shared__ short8 w1e8[128 * 3];
    short* w1s  = (short*)w1t8;
    short* w1es = (short*)w1e8;
    const int tid = threadIdx.x;

    for (int idx = tid; idx < 256 * HID; idx += 256) {
        int k = idx >> 7, col = idx & 127;
        w1s[col * 256 + (k ^ ((col & 7) << 3))] = f2bf(W1[idx]);
    }
    if (tid < HID) {
        int col = tid, base = col * 24;
        w1es[base + 0] = f2bf(W1[256 * HID + col]);
        w1es[base + 1] = f2bf(W1[257 * HID + col]);
        w1es[base + 2] = f2bf(b1[col]);
        #pragma unroll
        for (int j = 3; j < 16; ++j) w1es[base + j] = 0;
    }
    __syncthreads();

    const int lane = tid & 63, wid = tid >> 6, l31 = lane & 31, grp = lane >> 5;
    const bool is64 = (ei[1] == 0) && (ei[3] == 0) && (ei[5] == 0) && (ei[7] == 0);
    const long long* ei64 = (const long long*)ei;

    float w2v[4];
    #pragma unroll
    for (int nt = 0; nt < 4; ++nt) w2v[nt] = W2[nt * 32 + l31];
    const float b2v = b2[0];

    for (int ebase = blockIdx.x * EPW + wid * 32; ebase < NEDGES; ebase += NWG * EPW) {
        const int e = ebase + l31;
        const int u = is64 ? (int)ei64[e] : ei[e];
        const int v = is64 ? (int)ei64[NEDGES + e] : ei[NEDGES + e];
        const float ea0 = ea[2 * e], ea1 = ea[2 * e + 1];
        const float* pu32 = h + (size_t)u * HID + grp * 8;
        const float* pv32 = h + (size_t)v * HID + grp * 8;

        f32x16 acc[4];
        #pragma unroll
        for (int nt = 0; nt < 4; ++nt)
            #pragma unroll
            for (int r = 0; r < 16; ++r) acc[nt][r] = 0.f;

        #pragma unroll
        for (int ks = 0; ks < 17; ++ks) {
            short8 af;
            if (ks < 16) {
                const float* p = (ks < 8) ? (pu32 + ks * 16) : (pv32 + (ks - 8) * 16);
                f32x4v a0 = *(const f32x4v*)(p);
                f32x4v a1 = *(const f32x4v*)(p + 4);
                af[0]=f2bf(a0.x); af[1]=f2bf(a0.y); af[2]=f2bf(a0.z); af[3]=f2bf(a0.w);
                af[4]=f2bf(a1.x); af[5]=f2bf(a1.y); af[6]=f2bf(a1.z); af[7]=f2bf(a1.w);
            } else {
                af[0] = grp ? (short)0 : f2bf(ea0);
                af[1] = grp ? (short)0 : f2bf(ea1);
                af[2] = grp ? (short)0 : (short)0x3F80;
                af[3]=0; af[4]=0; af[5]=0; af[6]=0; af[7]=0;
            }
            #pragma unroll
            for (int nt = 0; nt < 4; ++nt) {
                const int col = nt * 32 + l31;
                short8 bf = (ks < 16)
                    ? w1t8[col * 32 + ((ks * 2 + grp) ^ (l31 & 7))]
                    : w1e8[col * 3 + grp];
                acc[nt] = __builtin_amdgcn_mfma_f32_32x32x16_bf16(af, bf, acc[nt], 0, 0, 0);
            }
        }

        float pr[16];
        #pragma unroll
        for (int r = 0; r < 16; ++r) {
            float s = fmaxf(acc[0][r], 0.f) * w2v[0];
            s = fmaf(fmaxf(acc[1][r], 0.f), w2v[1], s);
            s = fmaf(fmaxf(acc[2][r], 0.f), w2v[2], s);
            s = fmaf(fmaxf(acc[3][r], 0.f), w2v[3], s);
            pr[r] = s;
        }
        #define FOLD(MASK, A, B) { \
            const bool hi = (lane & MASK) != 0; \
            float snd = hi ? pr[A] : pr[B]; \
            float kp  = hi ? pr[B] : pr[A]; \
            pr[A] = kp + __shfl_xor(snd, MASK, 64); }
        #pragma unroll
        for (int i = 0; i < 8; ++i) FOLD(1, i, i + 8)
        #pragma unroll
        for (int i = 0; i < 4; ++i) FOLD(2, i, i + 4)
        #pragma unroll
        for (int i = 0; i < 2; ++i) FOLD(4, i, i + 2)
        FOLD(8, 0, 1)
        #undef FOLD
        float val = pr[0] + __shfl_xor(pr[0], 16, 64);
        const int reff = ((lane & 1) << 3) | ((lane & 2) << 1) | ((lane & 4) >> 1) | ((lane & 8) >> 3);
        const int row  = (reff & 3) + ((reff >> 2) << 3) + grp * 4;
        if ((lane & 16) == 0) out[ebase + row] = val + b2v;
    }
}

extern "C" void kernel_launch(void* const* d_in, const int* in_sizes, int n_in,
                              void* d_out, int out_size, void* d_ws, size_t ws_size,
                              hipStream_t stream) {
    const float* h  = (const float*)d_in[0];
    const int*   ei = (const int*)d_in[1];
    const float* ea = (const float*)d_in[2];
    const float* W1 = (const float*)d_in[3];
    const float* b1 = (const float*)d_in[4];
    const float* W2 = (const float*)d_in[5];
    const float* b2 = (const float*)d_in[6];
    float* out = (float*)d_out;

    const size_t need = (size_t)NNODES * 256 * sizeof(unsigned short);  // 25.6 MB
    if (ws_size >= need) {
        unsigned short* pre = (unsigned short*)d_ws;
        const int mblocks = (NNODES + 127) / 128;   // 391
        hipLaunchKernelGGL(gemm_pre, dim3(mblocks), dim3(256), 0, stream, h, W1, b1, pre);
        hipLaunchKernelGGL(edge_apply, dim3(NBLK), dim3(256), 0, stream,
                           pre, ei, ea, W1, W2, b2, out);
    } else {
        hipLaunchKernelGGL(edgehead_mono, dim3(NWG), dim3(256), 0, stream,
                           h, ei, ea, W1, b1, W2, b2, out);
    }
}